// Round 8
// baseline (202.058 us; speedup 1.0000x reference)
//
#include <hip/hip_runtime.h>

// VQ-VAE codebook lookup via bf16 MFMA + rigorous exact re-check.
// z_e [65536,64] f32, codebook [1024,64] f32.
// Out = concat(z_q [65536*64] f32, indices [65536] as f32).
//
// score s(n,k) = x.c - 0.5*c2[k] (= -dist/2 up to row-const). Sweep 1
// (MFMA bf16): per-row max m. Sweep 2: recompute (bit-identical), record
// codes with s >= m - DELTA_H (dist within 3.0 of min; bf16 error bound
// eps_dist <= 2*2^-8*||x||*||c|| < 1.0 << 3.0/2) -> candidate set provably
// contains exact argmin. 1 candidate -> done; else exact fp32 re-check with
// first-occurrence tie-break.
//
// Round-8 geometry: 16 rows/wave (one MFMA tile), 1024 blocks x 4 waves
// = 16 waves/CU; 2-deep named-set prefetch, branch-free (t+2)&63 clamp;
// c2 applied at max-time (not acc-init) to keep it off the MFMA chain.

typedef __attribute__((ext_vector_type(8))) short short8;
typedef __attribute__((ext_vector_type(4))) float f32x4;

#define N_ROWS  65536
#define D       64
#define K_CODES 1024
#define DELTA_H 1.5f
#define CAP     16

__device__ __forceinline__ unsigned short f2bf(float f) {
    unsigned u = __builtin_bit_cast(unsigned, f);
    unsigned r = (u + 0x7fffu + ((u >> 16) & 1u)) >> 16;   // RNE
    return (unsigned short)r;
}

__device__ __forceinline__ short8 cvt8(float4 u, float4 v) {
    short8 r;
    r[0] = (short)f2bf(u.x); r[1] = (short)f2bf(u.y);
    r[2] = (short)f2bf(u.z); r[3] = (short)f2bf(u.w);
    r[4] = (short)f2bf(v.x); r[5] = (short)f2bf(v.y);
    r[6] = (short)f2bf(v.z); r[7] = (short)f2bf(v.w);
    return r;
}

__device__ __forceinline__ float dist_f32(const float* __restrict__ xr,
                                          const float* __restrict__ cr,
                                          float c2k) {
    float a = 0.f, b = 0.f, c = 0.f, d = 0.f;
#pragma unroll
    for (int i = 0; i < 16; i += 2) {
        const float4 x0 = ((const float4*)xr)[i];
        const float4 c0 = ((const float4*)cr)[i];
        const float4 x1 = ((const float4*)xr)[i + 1];
        const float4 c1 = ((const float4*)cr)[i + 1];
        a = fmaf(x0.x, c0.x, a); b = fmaf(x0.y, c0.y, b);
        c = fmaf(x0.z, c0.z, c); d = fmaf(x0.w, c0.w, d);
        a = fmaf(x1.x, c1.x, a); b = fmaf(x1.y, c1.y, b);
        c = fmaf(x1.z, c1.z, c); d = fmaf(x1.w, c1.w, d);
    }
    const float dot = (a + b) + (c + d);
    return fmaf(-2.f, dot, c2k);
}

// prep: c2[k] (fp32) + codebook -> bf16. 8 blocks x 256, half-row/thread.
__global__ __launch_bounds__(256) void prep_kernel(const float* __restrict__ cb,
                                                   float* __restrict__ c2,
                                                   unsigned short* __restrict__ cbb) {
    const int gt = blockIdx.x * 256 + threadIdx.x;  // 0..2047
    const int c  = gt >> 1;
    const int h  = gt & 1;
    const float* src = cb + (size_t)c * D + h * 32;
    unsigned short* dst = cbb + (size_t)c * D + h * 32;
    float s = 0.f;
#pragma unroll
    for (int i = 0; i < 4; ++i) {
        const float4 u = ((const float4*)src)[2 * i];
        const float4 v = ((const float4*)src)[2 * i + 1];
        s = fmaf(u.x, u.x, s); s = fmaf(u.y, u.y, s);
        s = fmaf(u.z, u.z, s); s = fmaf(u.w, u.w, s);
        s = fmaf(v.x, v.x, s); s = fmaf(v.y, v.y, s);
        s = fmaf(v.z, v.z, s); s = fmaf(v.w, v.w, s);
        *(short8*)(dst + 8 * i) = cvt8(u, v);
    }
    const float o = __shfl_xor(s, 1);
    if (h == 0) c2[c] = s + o;
}

__global__ __launch_bounds__(256, 4) void vq_kernel(const float* __restrict__ z_e,
                                                    const float* __restrict__ cb,
                                                    const float* __restrict__ c2g,
                                                    const unsigned short* __restrict__ cbb,
                                                    float* __restrict__ out) {
    __shared__ int cnt_s[64];
    __shared__ int ovf_s[64];
    __shared__ int win_s[64];
    __shared__ int cand_s[64][CAP];

    const int tid   = threadIdx.x;
    const int w     = tid >> 6;        // wave -> 16-row tile
    const int lane  = tid & 63;
    const int lcol  = lane & 15;       // entity (row for A, code for B)
    const int lk    = lane >> 4;       // k-group
    const int rbase = blockIdx.x * 64 + w * 16;

    if (tid < 64) { cnt_s[tid] = 0; ovf_s[tid] = 0; }

    // A fragments: row rbase+lcol, k = 8*lk + (0..7) and 32 + same
    short8 a0, a1;
    {
        const float* p = z_e + (size_t)(rbase + lcol) * D + 8 * lk;
        a0 = cvt8(*(const float4*)p,        *(const float4*)(p + 4));
        a1 = cvt8(*(const float4*)(p + 32), *(const float4*)(p + 36));
    }
    __syncthreads();   // cnt/ovf init visible before sweep-2 atomics

    const unsigned short* bp  = cbb + (size_t)lcol * D + 8 * lk;
    const float*          c2p = c2g + lcol;

#define LOADSET(S, T)                                                 \
    b0##S = *(const short8*)(bp + (size_t)(T) * 1024);                \
    b1##S = *(const short8*)(bp + (size_t)(T) * 1024 + 32);           \
    c2##S = c2p[(T) * 16];

#define MFMASET(S)                                                            \
    f32x4 acc##S = {0.f, 0.f, 0.f, 0.f};                                      \
    acc##S = __builtin_amdgcn_mfma_f32_16x16x32_bf16(a0, b0##S, acc##S, 0,0,0); \
    acc##S = __builtin_amdgcn_mfma_f32_16x16x32_bf16(a1, b1##S, acc##S, 0,0,0);

    // ---- sweep 1: per-row max score ----
    float m0 = -3.4e38f, m1 = -3.4e38f, m2 = -3.4e38f, m3 = -3.4e38f;
    {
        short8 b0A, b1A, b0B, b1B;
        float c2A, c2B;
        LOADSET(A, 0); LOADSET(B, 1);
        for (int t = 0; t < 64; t += 2) {
            {
                MFMASET(A);
                const float cA = c2A;
                LOADSET(A, (t + 2) & 63);   // clamp wraps; value unused at end
                m0 = fmaxf(m0, fmaf(-0.5f, cA, accA[0]));
                m1 = fmaxf(m1, fmaf(-0.5f, cA, accA[1]));
                m2 = fmaxf(m2, fmaf(-0.5f, cA, accA[2]));
                m3 = fmaxf(m3, fmaf(-0.5f, cA, accA[3]));
            }
            {
                MFMASET(B);
                const float cB = c2B;
                LOADSET(B, (t + 3) & 63);
                m0 = fmaxf(m0, fmaf(-0.5f, cB, accB[0]));
                m1 = fmaxf(m1, fmaf(-0.5f, cB, accB[1]));
                m2 = fmaxf(m2, fmaf(-0.5f, cB, accB[2]));
                m3 = fmaxf(m3, fmaf(-0.5f, cB, accB[3]));
            }
        }
    }

    // reduce maxima across the 16 code-lanes sharing this lk-group
#pragma unroll
    for (int off = 1; off < 16; off <<= 1) {
        m0 = fmaxf(m0, __shfl_xor(m0, off));
        m1 = fmaxf(m1, __shfl_xor(m1, off));
        m2 = fmaxf(m2, __shfl_xor(m2, off));
        m3 = fmaxf(m3, __shfl_xor(m3, off));
    }
    const float gmin = fminf(fminf(m0, m1), fminf(m2, m3)) - DELTA_H;
    const float h0 = m0 - DELTA_H, h1 = m1 - DELTA_H;
    const float h2 = m2 - DELTA_H, h3 = m3 - DELTA_H;

#define REC(RL, CODE)                                                 \
    {                                                                 \
        const int sl = atomicAdd(&cnt_s[RL], 1);                      \
        if (sl < CAP) cand_s[RL][sl] = (CODE); else ovf_s[RL] = 1;    \
    }

#define SWEEP2(S, TT)                                                 \
    {                                                                 \
        const float t0 = fmaf(-0.5f, c##S, acc##S[0]);                \
        const float t1 = fmaf(-0.5f, c##S, acc##S[1]);                \
        const float t2 = fmaf(-0.5f, c##S, acc##S[2]);                \
        const float t3 = fmaf(-0.5f, c##S, acc##S[3]);                \
        const float tm = fmaxf(fmaxf(t0, t1), fmaxf(t2, t3));         \
        if (tm >= gmin) {                                             \
            const int code = (TT) * 16 + lcol;                        \
            const int rl   = w * 16 + 4 * lk;                         \
            if (t0 >= h0) REC(rl + 0, code);                          \
            if (t1 >= h1) REC(rl + 1, code);                          \
            if (t2 >= h2) REC(rl + 2, code);                          \
            if (t3 >= h3) REC(rl + 3, code);                          \
        }                                                             \
    }

    // ---- sweep 2: recompute (bit-identical), record candidates ----
    {
        short8 b0A, b1A, b0B, b1B;
        float c2A, c2B;
        LOADSET(A, 0); LOADSET(B, 1);
        for (int t = 0; t < 64; t += 2) {
            {
                MFMASET(A);
                const float cA = c2A;
                LOADSET(A, (t + 2) & 63);
                SWEEP2(A, t);
            }
            {
                MFMASET(B);
                const float cB = c2B;
                LOADSET(B, (t + 3) & 63);
                SWEEP2(B, t + 1);
            }
        }
    }
    __syncthreads();

    // ---- epilogue: resolve winner per row (exact fp32 when needed) ----
    if (tid < 64) {
        const int grow = blockIdx.x * 64 + tid;
        const int cnt  = cnt_s[tid];
        int win;
        if (ovf_s[tid] == 0 && cnt == 1) {
            win = cand_s[tid][0];
        } else {
            const float* xr = z_e + (size_t)grow * D;
            float bestd = 3.4e38f;
            int   bi    = K_CODES;
            if (ovf_s[tid]) {
                for (int k = 0; k < K_CODES; ++k) {
                    const float dk = dist_f32(xr, cb + (size_t)k * D, c2g[k]);
                    if (dk < bestd || (dk == bestd && k < bi)) { bestd = dk; bi = k; }
                }
            } else {
                for (int j = 0; j < cnt; ++j) {
                    const int k = cand_s[tid][j];
                    const float dk = dist_f32(xr, cb + (size_t)k * D, c2g[k]);
                    if (dk < bestd || (dk == bestd && k < bi)) { bestd = dk; bi = k; }
                }
            }
            win = bi;
        }
        win_s[tid] = win;
        out[(size_t)N_ROWS * D + grow] = (float)win;
    }
    __syncthreads();

    // ---- z_q gather+write: 4 threads per row, 4 float4 each ----
    {
        const int rl   = tid >> 2;
        const int q    = tid & 3;
        const int grow = blockIdx.x * 64 + rl;
        const float4* src = (const float4*)(cb + (size_t)win_s[rl] * D) + q * 4;
        float4*       dst = (float4*)(out + (size_t)grow * D) + q * 4;
#pragma unroll
        for (int i = 0; i < 4; ++i) dst[i] = src[i];
    }
}

extern "C" void kernel_launch(void* const* d_in, const int* in_sizes, int n_in,
                              void* d_out, int out_size, void* d_ws, size_t ws_size,
                              hipStream_t stream) {
    const float* z_e = (const float*)d_in[0];
    const float* cb  = (const float*)d_in[1];
    float* out = (float*)d_out;
    float*          c2  = (float*)d_ws;                          // 4 KB
    unsigned short* cbb = (unsigned short*)((char*)d_ws + 4096); // 128 KB

    hipLaunchKernelGGL(prep_kernel, dim3(8), dim3(256), 0, stream, cb, c2, cbb);
    hipLaunchKernelGGL(vq_kernel, dim3(N_ROWS / 64), dim3(256), 0, stream,
                       z_e, cb, c2, cbb, out);
}

// Round 9
// 120.735 us; speedup vs baseline: 1.6736x; 1.6736x over previous
//
#include <hip/hip_runtime.h>

// VQ-VAE codebook lookup via bf16 MFMA + rigorous exact re-check.
// z_e [65536,64] f32, codebook [1024,64] f32.
// Out = concat(z_q [65536*64] f32, indices [65536] as f32).
//
// score s(n,k) = x.c - 0.5*c2[k] (= -dist/2 up to row-const). Sweep 1
// (MFMA bf16): per-row max m (merged across waves). Sweep 2: recompute
// (bit-identical), record codes with s >= gmax - DELTA_H; candidate set
// provably contains the exact argmin (DELTA_H >= 2*eps,
// eps <= 2^-8*||x||*||c|| < 0.5). 1 candidate -> done; else exact fp32
// re-check, first-occurrence tie-break.
//
// Round-9 geometry (B-bandwidth attack): block = 4 waves x 64 SHARED rows;
// each wave holds 4 A-tiles (8 named short8 frags) and scans only its
// 256-code quarter -> 8 MFMAs per B-load-pair (4x reuse of R8, 2x of R7).
// B-traffic: 4096 waves x 64 KB = 256 MB. 1024 blocks -> 16 waves/CU.

typedef __attribute__((ext_vector_type(8))) short short8;
typedef __attribute__((ext_vector_type(4))) float f32x4;

#define N_ROWS  65536
#define D       64
#define K_CODES 1024
#define DELTA_H 1.5f
#define CAP     16

__device__ __forceinline__ unsigned short f2bf(float f) {
    unsigned u = __builtin_bit_cast(unsigned, f);
    unsigned r = (u + 0x7fffu + ((u >> 16) & 1u)) >> 16;   // RNE
    return (unsigned short)r;
}

__device__ __forceinline__ short8 cvt8(float4 u, float4 v) {
    short8 r;
    r[0] = (short)f2bf(u.x); r[1] = (short)f2bf(u.y);
    r[2] = (short)f2bf(u.z); r[3] = (short)f2bf(u.w);
    r[4] = (short)f2bf(v.x); r[5] = (short)f2bf(v.y);
    r[6] = (short)f2bf(v.z); r[7] = (short)f2bf(v.w);
    return r;
}

__device__ __forceinline__ float dist_f32(const float* __restrict__ xr,
                                          const float* __restrict__ cr,
                                          float c2k) {
    float a = 0.f, b = 0.f, c = 0.f, d = 0.f;
#pragma unroll
    for (int i = 0; i < 16; i += 2) {
        const float4 x0 = ((const float4*)xr)[i];
        const float4 c0 = ((const float4*)cr)[i];
        const float4 x1 = ((const float4*)xr)[i + 1];
        const float4 c1 = ((const float4*)cr)[i + 1];
        a = fmaf(x0.x, c0.x, a); b = fmaf(x0.y, c0.y, b);
        c = fmaf(x0.z, c0.z, c); d = fmaf(x0.w, c0.w, d);
        a = fmaf(x1.x, c1.x, a); b = fmaf(x1.y, c1.y, b);
        c = fmaf(x1.z, c1.z, c); d = fmaf(x1.w, c1.w, d);
    }
    const float dot = (a + b) + (c + d);
    return fmaf(-2.f, dot, c2k);
}

// prep: c2[k] (fp32) + codebook -> bf16. 8 blocks x 256, half-row/thread.
__global__ __launch_bounds__(256) void prep_kernel(const float* __restrict__ cb,
                                                   float* __restrict__ c2,
                                                   unsigned short* __restrict__ cbb) {
    const int gt = blockIdx.x * 256 + threadIdx.x;  // 0..2047
    const int c  = gt >> 1;
    const int h  = gt & 1;
    const float* src = cb + (size_t)c * D + h * 32;
    unsigned short* dst = cbb + (size_t)c * D + h * 32;
    float s = 0.f;
#pragma unroll
    for (int i = 0; i < 4; ++i) {
        const float4 u = ((const float4*)src)[2 * i];
        const float4 v = ((const float4*)src)[2 * i + 1];
        s = fmaf(u.x, u.x, s); s = fmaf(u.y, u.y, s);
        s = fmaf(u.z, u.z, s); s = fmaf(u.w, u.w, s);
        s = fmaf(v.x, v.x, s); s = fmaf(v.y, v.y, s);
        s = fmaf(v.z, v.z, s); s = fmaf(v.w, v.w, s);
        *(short8*)(dst + 8 * i) = cvt8(u, v);
    }
    const float o = __shfl_xor(s, 1);
    if (h == 0) c2[c] = s + o;
}

__global__ __launch_bounds__(256, 3) void vq_kernel(const float* __restrict__ z_e,
                                                    const float* __restrict__ cb,
                                                    const float* __restrict__ c2g,
                                                    const unsigned short* __restrict__ cbb,
                                                    float* __restrict__ out) {
    __shared__ float qmax_s[4][64];
    __shared__ float gmax_s[64];
    __shared__ int   cnt_s[64];
    __shared__ int   ovf_s[64];
    __shared__ int   win_s[64];
    __shared__ int   cand_s[64][CAP];

    const int tid   = threadIdx.x;
    const int w     = tid >> 6;        // wave -> code quarter
    const int lane  = tid & 63;
    const int lcol  = lane & 15;       // row within A-tile / code within B-tile
    const int lk    = lane >> 4;       // k-group
    const int rbase = blockIdx.x * 64;

    if (tid < 64) { cnt_s[tid] = 0; ovf_s[tid] = 0; }

    // ---- A fragments: tile i = rows rbase + 16*i + lcol (all waves same) ----
    short8 a0_0, a0_1, a0_2, a0_3, a1_0, a1_1, a1_2, a1_3;
#define LOADA(i)                                                               \
    {                                                                          \
        const float* p = z_e + (size_t)(rbase + 16 * (i) + lcol) * D + 8 * lk; \
        a0_##i = cvt8(*(const float4*)p,        *(const float4*)(p + 4));      \
        a1_##i = cvt8(*(const float4*)(p + 32), *(const float4*)(p + 36));     \
    }
    LOADA(0) LOADA(1) LOADA(2) LOADA(3)

    const unsigned short* bp  = cbb + (size_t)(w * 256 + lcol) * D + 8 * lk;
    const float*          c2p = c2g + w * 256 + lcol;

#define LOADB(T)                                                      \
    bn0 = *(const short8*)(bp + (size_t)(T) * 1024);                  \
    bn1 = *(const short8*)(bp + (size_t)(T) * 1024 + 32);             \
    c2n = c2p[(T) * 16];

#define MFMA8()                                                                   \
    f32x4 acc0 = {0.f, 0.f, 0.f, 0.f}, acc1 = {0.f, 0.f, 0.f, 0.f};              \
    f32x4 acc2 = {0.f, 0.f, 0.f, 0.f}, acc3 = {0.f, 0.f, 0.f, 0.f};              \
    acc0 = __builtin_amdgcn_mfma_f32_16x16x32_bf16(a0_0, bc0, acc0, 0, 0, 0);    \
    acc0 = __builtin_amdgcn_mfma_f32_16x16x32_bf16(a1_0, bc1, acc0, 0, 0, 0);    \
    acc1 = __builtin_amdgcn_mfma_f32_16x16x32_bf16(a0_1, bc0, acc1, 0, 0, 0);    \
    acc1 = __builtin_amdgcn_mfma_f32_16x16x32_bf16(a1_1, bc1, acc1, 0, 0, 0);    \
    acc2 = __builtin_amdgcn_mfma_f32_16x16x32_bf16(a0_2, bc0, acc2, 0, 0, 0);    \
    acc2 = __builtin_amdgcn_mfma_f32_16x16x32_bf16(a1_2, bc1, acc2, 0, 0, 0);    \
    acc3 = __builtin_amdgcn_mfma_f32_16x16x32_bf16(a0_3, bc0, acc3, 0, 0, 0);    \
    acc3 = __builtin_amdgcn_mfma_f32_16x16x32_bf16(a1_3, bc1, acc3, 0, 0, 0);

    // ---- sweep 1: per-row max score over this wave's quarter ----
    float m00 = -3.4e38f, m01 = -3.4e38f, m02 = -3.4e38f, m03 = -3.4e38f;
    float m10 = -3.4e38f, m11 = -3.4e38f, m12 = -3.4e38f, m13 = -3.4e38f;
    float m20 = -3.4e38f, m21 = -3.4e38f, m22 = -3.4e38f, m23 = -3.4e38f;
    float m30 = -3.4e38f, m31 = -3.4e38f, m32 = -3.4e38f, m33 = -3.4e38f;
    {
        short8 bc0, bc1, bn0, bn1;
        float c2c, c2n;
        LOADB(0);
        bc0 = bn0; bc1 = bn1; c2c = c2n;
        for (int tt = 0; tt < 16; ++tt) {
            if (tt < 15) { LOADB(tt + 1); }
            MFMA8();
            const float cc = c2c;
            m00 = fmaxf(m00, fmaf(-0.5f, cc, acc0[0]));
            m01 = fmaxf(m01, fmaf(-0.5f, cc, acc0[1]));
            m02 = fmaxf(m02, fmaf(-0.5f, cc, acc0[2]));
            m03 = fmaxf(m03, fmaf(-0.5f, cc, acc0[3]));
            m10 = fmaxf(m10, fmaf(-0.5f, cc, acc1[0]));
            m11 = fmaxf(m11, fmaf(-0.5f, cc, acc1[1]));
            m12 = fmaxf(m12, fmaf(-0.5f, cc, acc1[2]));
            m13 = fmaxf(m13, fmaf(-0.5f, cc, acc1[3]));
            m20 = fmaxf(m20, fmaf(-0.5f, cc, acc2[0]));
            m21 = fmaxf(m21, fmaf(-0.5f, cc, acc2[1]));
            m22 = fmaxf(m22, fmaf(-0.5f, cc, acc2[2]));
            m23 = fmaxf(m23, fmaf(-0.5f, cc, acc2[3]));
            m30 = fmaxf(m30, fmaf(-0.5f, cc, acc3[0]));
            m31 = fmaxf(m31, fmaf(-0.5f, cc, acc3[1]));
            m32 = fmaxf(m32, fmaf(-0.5f, cc, acc3[2]));
            m33 = fmaxf(m33, fmaf(-0.5f, cc, acc3[3]));
            bc0 = bn0; bc1 = bn1; c2c = c2n;
        }
    }

    // reduce maxima over the 16 code-lanes sharing this lk-group
#define RED16(OFF)                                     \
    m00 = fmaxf(m00, __shfl_xor(m00, OFF));            \
    m01 = fmaxf(m01, __shfl_xor(m01, OFF));            \
    m02 = fmaxf(m02, __shfl_xor(m02, OFF));            \
    m03 = fmaxf(m03, __shfl_xor(m03, OFF));            \
    m10 = fmaxf(m10, __shfl_xor(m10, OFF));            \
    m11 = fmaxf(m11, __shfl_xor(m11, OFF));            \
    m12 = fmaxf(m12, __shfl_xor(m12, OFF));            \
    m13 = fmaxf(m13, __shfl_xor(m13, OFF));            \
    m20 = fmaxf(m20, __shfl_xor(m20, OFF));            \
    m21 = fmaxf(m21, __shfl_xor(m21, OFF));            \
    m22 = fmaxf(m22, __shfl_xor(m22, OFF));            \
    m23 = fmaxf(m23, __shfl_xor(m23, OFF));            \
    m30 = fmaxf(m30, __shfl_xor(m30, OFF));            \
    m31 = fmaxf(m31, __shfl_xor(m31, OFF));            \
    m32 = fmaxf(m32, __shfl_xor(m32, OFF));            \
    m33 = fmaxf(m33, __shfl_xor(m33, OFF));
    RED16(1) RED16(2) RED16(4) RED16(8)

    if (lcol == 0) {
        qmax_s[w][ 0 + 4 * lk + 0] = m00;
        qmax_s[w][ 0 + 4 * lk + 1] = m01;
        qmax_s[w][ 0 + 4 * lk + 2] = m02;
        qmax_s[w][ 0 + 4 * lk + 3] = m03;
        qmax_s[w][16 + 4 * lk + 0] = m10;
        qmax_s[w][16 + 4 * lk + 1] = m11;
        qmax_s[w][16 + 4 * lk + 2] = m12;
        qmax_s[w][16 + 4 * lk + 3] = m13;
        qmax_s[w][32 + 4 * lk + 0] = m20;
        qmax_s[w][32 + 4 * lk + 1] = m21;
        qmax_s[w][32 + 4 * lk + 2] = m22;
        qmax_s[w][32 + 4 * lk + 3] = m23;
        qmax_s[w][48 + 4 * lk + 0] = m30;
        qmax_s[w][48 + 4 * lk + 1] = m31;
        qmax_s[w][48 + 4 * lk + 2] = m32;
        qmax_s[w][48 + 4 * lk + 3] = m33;
    }
    __syncthreads();
    if (tid < 64) {
        gmax_s[tid] = fmaxf(fmaxf(qmax_s[0][tid], qmax_s[1][tid]),
                            fmaxf(qmax_s[2][tid], qmax_s[3][tid]));
    }
    __syncthreads();

    // per-lane thresholds from GLOBAL maxima (broadcast LDS reads)
    const float h00 = gmax_s[ 0 + 4 * lk + 0] - DELTA_H;
    const float h01 = gmax_s[ 0 + 4 * lk + 1] - DELTA_H;
    const float h02 = gmax_s[ 0 + 4 * lk + 2] - DELTA_H;
    const float h03 = gmax_s[ 0 + 4 * lk + 3] - DELTA_H;
    const float h10 = gmax_s[16 + 4 * lk + 0] - DELTA_H;
    const float h11 = gmax_s[16 + 4 * lk + 1] - DELTA_H;
    const float h12 = gmax_s[16 + 4 * lk + 2] - DELTA_H;
    const float h13 = gmax_s[16 + 4 * lk + 3] - DELTA_H;
    const float h20 = gmax_s[32 + 4 * lk + 0] - DELTA_H;
    const float h21 = gmax_s[32 + 4 * lk + 1] - DELTA_H;
    const float h22 = gmax_s[32 + 4 * lk + 2] - DELTA_H;
    const float h23 = gmax_s[32 + 4 * lk + 3] - DELTA_H;
    const float h30 = gmax_s[48 + 4 * lk + 0] - DELTA_H;
    const float h31 = gmax_s[48 + 4 * lk + 1] - DELTA_H;
    const float h32 = gmax_s[48 + 4 * lk + 2] - DELTA_H;
    const float h33 = gmax_s[48 + 4 * lk + 3] - DELTA_H;
    const float gmin = fminf(
        fminf(fminf(fminf(h00, h01), fminf(h02, h03)),
              fminf(fminf(h10, h11), fminf(h12, h13))),
        fminf(fminf(fminf(h20, h21), fminf(h22, h23)),
              fminf(fminf(h30, h31), fminf(h32, h33))));

#define REC(RL, CODE)                                                 \
    {                                                                 \
        const int sl = atomicAdd(&cnt_s[RL], 1);                      \
        if (sl < CAP) cand_s[RL][sl] = (CODE); else ovf_s[RL] = 1;    \
    }

    // ---- sweep 2: recompute (bit-identical), record candidates ----
    {
        short8 bc0, bc1, bn0, bn1;
        float c2c, c2n;
        LOADB(0);
        bc0 = bn0; bc1 = bn1; c2c = c2n;
        for (int tt = 0; tt < 16; ++tt) {
            if (tt < 15) { LOADB(tt + 1); }
            MFMA8();
            const float cc = c2c;
            const float t00 = fmaf(-0.5f, cc, acc0[0]);
            const float t01 = fmaf(-0.5f, cc, acc0[1]);
            const float t02 = fmaf(-0.5f, cc, acc0[2]);
            const float t03 = fmaf(-0.5f, cc, acc0[3]);
            const float t10 = fmaf(-0.5f, cc, acc1[0]);
            const float t11 = fmaf(-0.5f, cc, acc1[1]);
            const float t12 = fmaf(-0.5f, cc, acc1[2]);
            const float t13 = fmaf(-0.5f, cc, acc1[3]);
            const float t20 = fmaf(-0.5f, cc, acc2[0]);
            const float t21 = fmaf(-0.5f, cc, acc2[1]);
            const float t22 = fmaf(-0.5f, cc, acc2[2]);
            const float t23 = fmaf(-0.5f, cc, acc2[3]);
            const float t30 = fmaf(-0.5f, cc, acc3[0]);
            const float t31 = fmaf(-0.5f, cc, acc3[1]);
            const float t32 = fmaf(-0.5f, cc, acc3[2]);
            const float t33 = fmaf(-0.5f, cc, acc3[3]);
            const float tm = fmaxf(
                fmaxf(fmaxf(fmaxf(t00, t01), fmaxf(t02, t03)),
                      fmaxf(fmaxf(t10, t11), fmaxf(t12, t13))),
                fmaxf(fmaxf(fmaxf(t20, t21), fmaxf(t22, t23)),
                      fmaxf(fmaxf(t30, t31), fmaxf(t32, t33))));
            if (tm >= gmin) {
                const int code = (w << 8) + (tt << 4) + lcol;
                if (t00 >= h00) REC( 0 + 4 * lk + 0, code);
                if (t01 >= h01) REC( 0 + 4 * lk + 1, code);
                if (t02 >= h02) REC( 0 + 4 * lk + 2, code);
                if (t03 >= h03) REC( 0 + 4 * lk + 3, code);
                if (t10 >= h10) REC(16 + 4 * lk + 0, code);
                if (t11 >= h11) REC(16 + 4 * lk + 1, code);
                if (t12 >= h12) REC(16 + 4 * lk + 2, code);
                if (t13 >= h13) REC(16 + 4 * lk + 3, code);
                if (t20 >= h20) REC(32 + 4 * lk + 0, code);
                if (t21 >= h21) REC(32 + 4 * lk + 1, code);
                if (t22 >= h22) REC(32 + 4 * lk + 2, code);
                if (t23 >= h23) REC(32 + 4 * lk + 3, code);
                if (t30 >= h30) REC(48 + 4 * lk + 0, code);
                if (t31 >= h31) REC(48 + 4 * lk + 1, code);
                if (t32 >= h32) REC(48 + 4 * lk + 2, code);
                if (t33 >= h33) REC(48 + 4 * lk + 3, code);
            }
            bc0 = bn0; bc1 = bn1; c2c = c2n;
        }
    }
    __syncthreads();

    // ---- epilogue: resolve winner per row (exact fp32 when needed) ----
    if (tid < 64) {
        const int grow = rbase + tid;
        const int cnt  = cnt_s[tid];
        int win;
        if (ovf_s[tid] == 0 && cnt == 1) {
            win = cand_s[tid][0];
        } else {
            const float* xr = z_e + (size_t)grow * D;
            float bestd = 3.4e38f;
            int   bi    = K_CODES;
            if (ovf_s[tid]) {
                for (int k = 0; k < K_CODES; ++k) {
                    const float dk = dist_f32(xr, cb + (size_t)k * D, c2g[k]);
                    if (dk < bestd || (dk == bestd && k < bi)) { bestd = dk; bi = k; }
                }
            } else {
                for (int j = 0; j < cnt; ++j) {
                    const int k = cand_s[tid][j];
                    const float dk = dist_f32(xr, cb + (size_t)k * D, c2g[k]);
                    if (dk < bestd || (dk == bestd && k < bi)) { bestd = dk; bi = k; }
                }
            }
            win = bi;
        }
        win_s[tid] = win;
        out[(size_t)N_ROWS * D + grow] = (float)win;
    }
    __syncthreads();

    // ---- z_q gather+write: 4 threads per row, 4 float4 each ----
    {
        const int rl   = tid >> 2;
        const int q    = tid & 3;
        const int grow = rbase + rl;
        const float4* src = (const float4*)(cb + (size_t)win_s[rl] * D) + q * 4;
        float4*       dst = (float4*)(out + (size_t)grow * D) + q * 4;
#pragma unroll
        for (int i = 0; i < 4; ++i) dst[i] = src[i];
    }
}

extern "C" void kernel_launch(void* const* d_in, const int* in_sizes, int n_in,
                              void* d_out, int out_size, void* d_ws, size_t ws_size,
                              hipStream_t stream) {
    const float* z_e = (const float*)d_in[0];
    const float* cb  = (const float*)d_in[1];
    float* out = (float*)d_out;
    float*          c2  = (float*)d_ws;                          // 4 KB
    unsigned short* cbb = (unsigned short*)((char*)d_ws + 4096); // 128 KB

    hipLaunchKernelGGL(prep_kernel, dim3(8), dim3(256), 0, stream, cb, c2, cbb);
    hipLaunchKernelGGL(vq_kernel, dim3(N_ROWS / 64), dim3(256), 0, stream,
                       z_e, cb, c2, cbb, out);
}

// Round 10
// 118.988 us; speedup vs baseline: 1.6981x; 1.0147x over previous
//
#include <hip/hip_runtime.h>

// VQ-VAE codebook lookup via bf16 MFMA + rigorous exact re-check.
// z_e [65536,64] f32, codebook [1024,64] f32.
// Out = concat(z_q [65536*64] f32, indices [65536] as f32).
//
// score s(n,k) = x.c - 0.5*c2[k] (= -dist/2 up to row-const). Sweep 1
// (MFMA bf16, acc init = -c2/2): per-row max m (merged across waves via
// LDS). Sweep 2: recompute (bit-identical), record codes with
// s >= gmax - DELTA_H; candidate set provably contains the exact argmin
// (DELTA_H = 1.5 >= 2*eps, eps <= 2^-8*||x||*||c|| < 0.5). 1 candidate ->
// done; else exact fp32 re-check, first-occurrence tie-break.
//
// Round-10 geometry: block = 4 waves x 128 SHARED rows; each wave holds
// 8 A-tiles (16 named short8 frags) and scans its 256-code quarter ->
// 16 MFMAs per B-load-pair. B-traffic: 2048 waves x 64 KB = 128 MB
// (1/2 of R9, 1/4 of R7). 512 blocks -> 2 blocks/CU, 8 waves/CU.

typedef __attribute__((ext_vector_type(8))) short short8;
typedef __attribute__((ext_vector_type(4))) float f32x4;

#define N_ROWS  65536
#define D       64
#define K_CODES 1024
#define DELTA_H 1.5f
#define CAP     16

#define TILES(F) F(0) F(1) F(2) F(3) F(4) F(5) F(6) F(7)

__device__ __forceinline__ unsigned short f2bf(float f) {
    unsigned u = __builtin_bit_cast(unsigned, f);
    unsigned r = (u + 0x7fffu + ((u >> 16) & 1u)) >> 16;   // RNE
    return (unsigned short)r;
}

__device__ __forceinline__ short8 cvt8(float4 u, float4 v) {
    short8 r;
    r[0] = (short)f2bf(u.x); r[1] = (short)f2bf(u.y);
    r[2] = (short)f2bf(u.z); r[3] = (short)f2bf(u.w);
    r[4] = (short)f2bf(v.x); r[5] = (short)f2bf(v.y);
    r[6] = (short)f2bf(v.z); r[7] = (short)f2bf(v.w);
    return r;
}

__device__ __forceinline__ float dist_f32(const float* __restrict__ xr,
                                          const float* __restrict__ cr,
                                          float c2k) {
    float a = 0.f, b = 0.f, c = 0.f, d = 0.f;
#pragma unroll
    for (int i = 0; i < 16; i += 2) {
        const float4 x0 = ((const float4*)xr)[i];
        const float4 c0 = ((const float4*)cr)[i];
        const float4 x1 = ((const float4*)xr)[i + 1];
        const float4 c1 = ((const float4*)cr)[i + 1];
        a = fmaf(x0.x, c0.x, a); b = fmaf(x0.y, c0.y, b);
        c = fmaf(x0.z, c0.z, c); d = fmaf(x0.w, c0.w, d);
        a = fmaf(x1.x, c1.x, a); b = fmaf(x1.y, c1.y, b);
        c = fmaf(x1.z, c1.z, c); d = fmaf(x1.w, c1.w, d);
    }
    const float dot = (a + b) + (c + d);
    return fmaf(-2.f, dot, c2k);
}

// prep: c2[k] (fp32) + codebook -> bf16. 16 blocks x 256, quarter-row/thread.
__global__ __launch_bounds__(256) void prep_kernel(const float* __restrict__ cb,
                                                   float* __restrict__ c2,
                                                   unsigned short* __restrict__ cbb) {
    const int gt = blockIdx.x * 256 + threadIdx.x;  // 0..4095
    const int c  = gt >> 2;
    const int q  = gt & 3;
    const float* src = cb + (size_t)c * D + q * 16;
    unsigned short* dst = cbb + (size_t)c * D + q * 16;
    float s = 0.f;
#pragma unroll
    for (int i = 0; i < 2; ++i) {
        const float4 u = ((const float4*)src)[2 * i];
        const float4 v = ((const float4*)src)[2 * i + 1];
        s = fmaf(u.x, u.x, s); s = fmaf(u.y, u.y, s);
        s = fmaf(u.z, u.z, s); s = fmaf(u.w, u.w, s);
        s = fmaf(v.x, v.x, s); s = fmaf(v.y, v.y, s);
        s = fmaf(v.z, v.z, s); s = fmaf(v.w, v.w, s);
        *(short8*)(dst + 8 * i) = cvt8(u, v);
    }
    s += __shfl_xor(s, 1);
    s += __shfl_xor(s, 2);
    if (q == 0) c2[c] = s;
}

__global__ __launch_bounds__(256, 2) void vq_kernel(const float* __restrict__ z_e,
                                                    const float* __restrict__ cb,
                                                    const float* __restrict__ c2g,
                                                    const unsigned short* __restrict__ cbb,
                                                    float* __restrict__ out) {
    __shared__ float qmax_s[4][128];
    __shared__ float gmax_s[128];
    __shared__ int   cnt_s[128];
    __shared__ int   ovf_s[128];
    __shared__ int   win_s[128];
    __shared__ int   cand_s[128][CAP];

    const int tid   = threadIdx.x;
    const int w     = tid >> 6;        // wave -> code quarter
    const int lane  = tid & 63;
    const int lcol  = lane & 15;       // row within A-tile / code within B-tile
    const int lk    = lane >> 4;       // k-group
    const int rbase = blockIdx.x * 128;

    if (tid < 128) { cnt_s[tid] = 0; ovf_s[tid] = 0; }

    // ---- A fragments: tile i = rows rbase + 16*i + lcol (all waves same) ----
#define DECLA(i) short8 a0_##i, a1_##i;
    TILES(DECLA)
#define LOADA(i)                                                               \
    {                                                                          \
        const float* p = z_e + (size_t)(rbase + 16 * (i) + lcol) * D + 8 * lk; \
        a0_##i = cvt8(*(const float4*)p,        *(const float4*)(p + 4));      \
        a1_##i = cvt8(*(const float4*)(p + 32), *(const float4*)(p + 36));     \
    }
    TILES(LOADA)

    const unsigned short* bp  = cbb + (size_t)(w * 256 + lcol) * D + 8 * lk;
    const float*          c2p = c2g + w * 256 + lcol;

#define LOADB(T)                                                      \
    bn0 = *(const short8*)(bp + (size_t)(T) * 1024);                  \
    bn1 = *(const short8*)(bp + (size_t)(T) * 1024 + 32);             \
    c2n = c2p[(T) * 16];

    // acc init = -0.5*c2 (R7 trick): score lands directly in acc.
#define MFMA16()                                                               \
    const float sv = -0.5f * c2c;                                              \
    _Pragma("unroll")                                                          \
    TILES(DOMFMA)

#define DOMFMA(i)                                                              \
    f32x4 acc##i = {sv, sv, sv, sv};                                           \
    acc##i = __builtin_amdgcn_mfma_f32_16x16x32_bf16(a0_##i, bc0, acc##i, 0, 0, 0); \
    acc##i = __builtin_amdgcn_mfma_f32_16x16x32_bf16(a1_##i, bc1, acc##i, 0, 0, 0);

    // ---- sweep 1: per-row max score over this wave's quarter ----
#define DECLM(i) float m##i##0 = -3.4e38f, m##i##1 = -3.4e38f,                 \
                       m##i##2 = -3.4e38f, m##i##3 = -3.4e38f;
    TILES(DECLM)
    {
        short8 bc0, bc1, bn0, bn1;
        float c2c, c2n;
        LOADB(0);
        bc0 = bn0; bc1 = bn1; c2c = c2n;
        for (int tt = 0; tt < 16; ++tt) {
            if (tt < 15) { LOADB(tt + 1); }
            {
                const float sv = -0.5f * c2c;
#define DOTILE1(i)                                                                    \
                f32x4 acc##i = {sv, sv, sv, sv};                                      \
                acc##i = __builtin_amdgcn_mfma_f32_16x16x32_bf16(a0_##i, bc0, acc##i, 0, 0, 0); \
                acc##i = __builtin_amdgcn_mfma_f32_16x16x32_bf16(a1_##i, bc1, acc##i, 0, 0, 0); \
                m##i##0 = fmaxf(m##i##0, acc##i[0]);                                  \
                m##i##1 = fmaxf(m##i##1, acc##i[1]);                                  \
                m##i##2 = fmaxf(m##i##2, acc##i[2]);                                  \
                m##i##3 = fmaxf(m##i##3, acc##i[3]);
                TILES(DOTILE1)
            }
            bc0 = bn0; bc1 = bn1; c2c = c2n;
        }
    }

    // reduce maxima over the 16 code-lanes sharing this lk-group
#define REDT(i)                                                       \
    m##i##0 = fmaxf(m##i##0, __shfl_xor(m##i##0, OFF));               \
    m##i##1 = fmaxf(m##i##1, __shfl_xor(m##i##1, OFF));               \
    m##i##2 = fmaxf(m##i##2, __shfl_xor(m##i##2, OFF));               \
    m##i##3 = fmaxf(m##i##3, __shfl_xor(m##i##3, OFF));
    {
#define OFF 1
        TILES(REDT)
#undef OFF
#define OFF 2
        TILES(REDT)
#undef OFF
#define OFF 4
        TILES(REDT)
#undef OFF
#define OFF 8
        TILES(REDT)
#undef OFF
    }

    if (lcol == 0) {
#define WRQ(i)                                                        \
        qmax_s[w][16 * (i) + 4 * lk + 0] = m##i##0;                   \
        qmax_s[w][16 * (i) + 4 * lk + 1] = m##i##1;                   \
        qmax_s[w][16 * (i) + 4 * lk + 2] = m##i##2;                   \
        qmax_s[w][16 * (i) + 4 * lk + 3] = m##i##3;
        TILES(WRQ)
    }
    __syncthreads();
    if (tid < 128) {
        gmax_s[tid] = fmaxf(fmaxf(qmax_s[0][tid], qmax_s[1][tid]),
                            fmaxf(qmax_s[2][tid], qmax_s[3][tid]));
    }
    __syncthreads();

    // per-lane thresholds from GLOBAL maxima (broadcast LDS reads)
#define DECLH(i)                                                      \
    const float h##i##0 = gmax_s[16 * (i) + 4 * lk + 0] - DELTA_H;    \
    const float h##i##1 = gmax_s[16 * (i) + 4 * lk + 1] - DELTA_H;    \
    const float h##i##2 = gmax_s[16 * (i) + 4 * lk + 2] - DELTA_H;    \
    const float h##i##3 = gmax_s[16 * (i) + 4 * lk + 3] - DELTA_H;
    TILES(DECLH)
#define MIN4(i) fminf(fminf(h##i##0, h##i##1), fminf(h##i##2, h##i##3))
    const float gmin = fminf(
        fminf(fminf(MIN4(0), MIN4(1)), fminf(MIN4(2), MIN4(3))),
        fminf(fminf(MIN4(4), MIN4(5)), fminf(MIN4(6), MIN4(7))));

#define REC(RL, CODE)                                                 \
    {                                                                 \
        const int sl = atomicAdd(&cnt_s[RL], 1);                      \
        if (sl < CAP) cand_s[RL][sl] = (CODE); else ovf_s[RL] = 1;    \
    }

    // ---- sweep 2: recompute (bit-identical), record candidates ----
    {
        short8 bc0, bc1, bn0, bn1;
        float c2c, c2n;
        LOADB(0);
        bc0 = bn0; bc1 = bn1; c2c = c2n;
        for (int tt = 0; tt < 16; ++tt) {
            if (tt < 15) { LOADB(tt + 1); }
            {
                const float sv = -0.5f * c2c;
#define DOTILE2(i)                                                                    \
                f32x4 acc##i = {sv, sv, sv, sv};                                      \
                acc##i = __builtin_amdgcn_mfma_f32_16x16x32_bf16(a0_##i, bc0, acc##i, 0, 0, 0); \
                acc##i = __builtin_amdgcn_mfma_f32_16x16x32_bf16(a1_##i, bc1, acc##i, 0, 0, 0);
                TILES(DOTILE2)
#define MAX4(i) fmaxf(fmaxf(acc##i[0], acc##i[1]), fmaxf(acc##i[2], acc##i[3]))
                const float tm = fmaxf(
                    fmaxf(fmaxf(MAX4(0), MAX4(1)), fmaxf(MAX4(2), MAX4(3))),
                    fmaxf(fmaxf(MAX4(4), MAX4(5)), fmaxf(MAX4(6), MAX4(7))));
                if (tm >= gmin) {
                    const int code = (w << 8) + (tt << 4) + lcol;
#define CHK(i)                                                            \
                    if (acc##i[0] >= h##i##0) REC(16 * (i) + 4 * lk + 0, code); \
                    if (acc##i[1] >= h##i##1) REC(16 * (i) + 4 * lk + 1, code); \
                    if (acc##i[2] >= h##i##2) REC(16 * (i) + 4 * lk + 2, code); \
                    if (acc##i[3] >= h##i##3) REC(16 * (i) + 4 * lk + 3, code);
                    TILES(CHK)
                }
            }
            bc0 = bn0; bc1 = bn1; c2c = c2n;
        }
    }
    __syncthreads();

    // ---- epilogue: resolve winner per row (exact fp32 when needed) ----
    if (tid < 128) {
        const int grow = rbase + tid;
        const int cnt  = cnt_s[tid];
        int win;
        if (ovf_s[tid] == 0 && cnt == 1) {
            win = cand_s[tid][0];
        } else {
            const float* xr = z_e + (size_t)grow * D;
            float bestd = 3.4e38f;
            int   bi    = K_CODES;
            if (ovf_s[tid]) {
                for (int k = 0; k < K_CODES; ++k) {
                    const float dk = dist_f32(xr, cb + (size_t)k * D, c2g[k]);
                    if (dk < bestd || (dk == bestd && k < bi)) { bestd = dk; bi = k; }
                }
            } else {
                for (int j = 0; j < cnt; ++j) {
                    const int k = cand_s[tid][j];
                    const float dk = dist_f32(xr, cb + (size_t)k * D, c2g[k]);
                    if (dk < bestd || (dk == bestd && k < bi)) { bestd = dk; bi = k; }
                }
            }
            win = bi;
        }
        win_s[tid] = win;
        out[(size_t)N_ROWS * D + grow] = (float)win;
    }
    __syncthreads();

    // ---- z_q gather+write: 2 threads per row, 8 float4 each ----
    {
        const int rl   = tid >> 1;
        const int hf   = tid & 1;
        const int grow = rbase + rl;
        const float4* src = (const float4*)(cb + (size_t)win_s[rl] * D) + hf * 8;
        float4*       dst = (float4*)(out + (size_t)grow * D) + hf * 8;
#pragma unroll
        for (int i = 0; i < 8; ++i) dst[i] = src[i];
    }
}

extern "C" void kernel_launch(void* const* d_in, const int* in_sizes, int n_in,
                              void* d_out, int out_size, void* d_ws, size_t ws_size,
                              hipStream_t stream) {
    const float* z_e = (const float*)d_in[0];
    const float* cb  = (const float*)d_in[1];
    float* out = (float*)d_out;
    float*          c2  = (float*)d_ws;                          // 4 KB
    unsigned short* cbb = (unsigned short*)((char*)d_ws + 4096); // 128 KB

    hipLaunchKernelGGL(prep_kernel, dim3(16), dim3(256), 0, stream, cb, c2, cbb);
    hipLaunchKernelGGL(vq_kernel, dim3(N_ROWS / 128), dim3(256), 0, stream,
                       z_e, cb, c2, cbb, out);
}